// Round 1
// baseline (242.087 us; speedup 1.0000x reference)
//
#include <hip/hip_runtime.h>

// Problem constants (B,T,D) = (128, 1024, 64), fp32 in/out.
constexpr int BX    = 128;
constexpr int TT    = 1024;
constexpr int DDIM  = 64;
constexpr int NPAIR = BX * BX;          // 16384
constexpr int LCH   = 32;               // time-chunk length
constexpr int NCH   = TT / LCH;         // 32 chunks
constexpr float DT_INV = 1023.0f;       // 1/dt

// Kernel A: per (32x32 pair tile, 32-step time chunk):
//   Z[p][t] = 1 + <dX_i(t-1), dY_j(t-1)> / dt   (Z[p][0] = 1)
//   writes within-chunk inclusive cumprod to out[p][t0..t0+31]
//   writes chunk-total product to P[c][p]
__global__ __launch_bounds__(256, 2) void zchunk_kernel(const float* __restrict__ X,
                                                        const float* __restrict__ Y,
                                                        float* __restrict__ out,
                                                        float* __restrict__ P)
{
    __shared__ float dXl[32][68];   // +4 pad breaks bank aliasing
    __shared__ float dYl[32][68];

    const int i0 = blockIdx.x * 32;
    const int j0 = blockIdx.y * 32;
    const int t0 = blockIdx.z * LCH;
    const int tid = (int)threadIdx.x;
    const int ti = tid >> 4;        // 0..15
    const int tj = tid & 15;        // 0..15

    float cum00 = 1.f, cum01 = 1.f, cum10 = 1.f, cum11 = 1.f;
    const int pbase = (i0 + ti) * BX + (j0 + tj);

    for (int tseg = 0; tseg < LCH; tseg += 8) {
        float h00[8], h01[8], h10[8], h11[8];
#pragma unroll
        for (int h = 0; h < 8; ++h) {
            const int s = t0 + tseg + h - 1;   // source step index (t-1)
            float z00 = 1.f, z01 = 1.f, z10 = 1.f, z11 = 1.f;
            if (s >= 0) {                       // block-uniform branch (only c=0,t=0 skips)
                // ---- stage dX/dY tiles (32 rows x 64 floats each) ----
#pragma unroll
                for (int k = tid; k < 512; k += 256) {
                    const int r  = k >> 4;
                    const int c4 = (k & 15) << 2;
                    const float* xp = X + ((size_t)(i0 + r) * TT + s) * DDIM + c4;
                    const float4 xa = *(const float4*)xp;
                    const float4 xb = *(const float4*)(xp + DDIM);
                    *(float4*)&dXl[r][c4] =
                        make_float4(xb.x - xa.x, xb.y - xa.y, xb.z - xa.z, xb.w - xa.w);
                    const float* yp = Y + ((size_t)(j0 + r) * TT + s) * DDIM + c4;
                    const float4 ya = *(const float4*)yp;
                    const float4 yb = *(const float4*)(yp + DDIM);
                    *(float4*)&dYl[r][c4] =
                        make_float4(yb.x - ya.x, yb.y - ya.y, yb.z - ya.z, yb.w - ya.w);
                }
                __syncthreads();
                // ---- 2x2 micro-tile dot products over D=64 ----
                float d00 = 0.f, d01 = 0.f, d10 = 0.f, d11 = 0.f;
#pragma unroll
                for (int dd = 0; dd < DDIM; dd += 4) {
                    const float4 xa = *(const float4*)&dXl[ti][dd];
                    const float4 xb = *(const float4*)&dXl[ti + 16][dd];
                    const float4 ya = *(const float4*)&dYl[tj][dd];
                    const float4 yb = *(const float4*)&dYl[tj + 16][dd];
                    d00 += xa.x * ya.x + xa.y * ya.y + xa.z * ya.z + xa.w * ya.w;
                    d01 += xa.x * yb.x + xa.y * yb.y + xa.z * yb.z + xa.w * yb.w;
                    d10 += xb.x * ya.x + xb.y * ya.y + xb.z * ya.z + xb.w * ya.w;
                    d11 += xb.x * yb.x + xb.y * yb.y + xb.z * yb.z + xb.w * yb.w;
                }
                z00 = fmaf(d00, DT_INV, 1.f);
                z01 = fmaf(d01, DT_INV, 1.f);
                z10 = fmaf(d10, DT_INV, 1.f);
                z11 = fmaf(d11, DT_INV, 1.f);
                __syncthreads();   // protect LDS tiles before next staging
            }
            cum00 *= z00; cum01 *= z01; cum10 *= z10; cum11 *= z11;
            h00[h] = cum00; h01[h] = cum01; h10[h] = cum10; h11[h] = cum11;
        }
        // ---- flush 8 cumulative values per pair (32B contiguous per pair) ----
        const int tb = t0 + tseg;
        float* o = out + (size_t)pbase * TT + tb;
        *(float4*)(o)     = make_float4(h00[0], h00[1], h00[2], h00[3]);
        *(float4*)(o + 4) = make_float4(h00[4], h00[5], h00[6], h00[7]);
        o = out + (size_t)(pbase + 16) * TT + tb;
        *(float4*)(o)     = make_float4(h01[0], h01[1], h01[2], h01[3]);
        *(float4*)(o + 4) = make_float4(h01[4], h01[5], h01[6], h01[7]);
        o = out + (size_t)(pbase + 16 * BX) * TT + tb;
        *(float4*)(o)     = make_float4(h10[0], h10[1], h10[2], h10[3]);
        *(float4*)(o + 4) = make_float4(h10[4], h10[5], h10[6], h10[7]);
        o = out + (size_t)(pbase + 16 * BX + 16) * TT + tb;
        *(float4*)(o)     = make_float4(h11[0], h11[1], h11[2], h11[3]);
        *(float4*)(o + 4) = make_float4(h11[4], h11[5], h11[6], h11[7]);
    }

    // chunk-total products -> P[c][pair]
    const int c = blockIdx.z;
    P[c * NPAIR + pbase]                = cum00;
    P[c * NPAIR + pbase + 16]           = cum01;
    P[c * NPAIR + pbase + 16 * BX]      = cum10;
    P[c * NPAIR + pbase + 16 * BX + 16] = cum11;
}

// Kernel B: in-place exclusive prefix product over chunks per pair.
__global__ __launch_bounds__(256) void scan_kernel(float* __restrict__ P)
{
    const int p = blockIdx.x * 256 + (int)threadIdx.x;  // 0..16383
    float run = 1.f;
    for (int c = 0; c < NCH; ++c) {
        const int idx = c * NPAIR + p;
        const float v = P[idx];
        P[idx] = run;
        run *= v;
    }
}

// Kernel C: out[p][t] *= E[t/LCH][p]  (fully coalesced float4 pass)
__global__ __launch_bounds__(256) void scale_kernel(float* __restrict__ out,
                                                    const float* __restrict__ P)
{
    const size_t g    = (size_t)blockIdx.x * 256 + threadIdx.x;
    const size_t base = g * 4;                 // element index, 4 | base
    const int p = (int)(base >> 10);           // /1024
    const int t = (int)(base & 1023);
    const int c = t >> 5;                      // /LCH
    const float f = P[c * NPAIR + p];
    float4 v = *(float4*)(out + base);
    v.x *= f; v.y *= f; v.z *= f; v.w *= f;
    *(float4*)(out + base) = v;
}

extern "C" void kernel_launch(void* const* d_in, const int* in_sizes, int n_in,
                              void* d_out, int out_size, void* d_ws, size_t ws_size,
                              hipStream_t stream)
{
    const float* X = (const float*)d_in[0];   // (128, 1024, 64) fp32
    const float* Y = (const float*)d_in[1];   // (128, 1024, 64) fp32
    float* out = (float*)d_out;               // (128, 128, 1024) fp32
    float* P   = (float*)d_ws;                // needs NCH*NPAIR*4 = 2 MB scratch

    zchunk_kernel<<<dim3(4, 4, NCH), 256, 0, stream>>>(X, Y, out, P);
    scan_kernel<<<dim3(NPAIR / 256), 256, 0, stream>>>(P);
    scale_kernel<<<dim3((16777216 / 4) / 256), 256, 0, stream>>>(out, P);
}